// Round 1
// baseline (112.527 us; speedup 1.0000x reference)
//
#include <hip/hip_runtime.h>
#include <hip/hip_bf16.h>

typedef __bf16 bf16x8 __attribute__((ext_vector_type(8)));
typedef float  f32x16 __attribute__((ext_vector_type(16)));

constexpr int QN  = 128;   // query rows
constexpr int KN  = 2048;  // memory rows
constexpr int D5  = 768;
constexpr int SL  = 32;    // seq_len (t and s extent)
constexpr int ZD  = 24;    // per-token sub-dim
constexpr int KCH = 16;    // k's per block

// Per-pair: S[t][s] = sum_d Q[t][d]*K[s][d] via mfma_f32_32x32x16_bf16 (d padded to 32).
// S^T computed with a second MFMA (operands swapped) so BOTH max-pools are per-lane
// register reductions in the C layout (col=lane&31, rows in the 16 acc regs).
__global__ __launch_bounds__(256) void matcher_kernel(const float* __restrict__ tgt,
                                                      const float* __restrict__ mem,
                                                      float* __restrict__ out)
{
    // Fragment-ordered K chunk: per k, 2 chunks x 64 lanes x 8 bf16 (16B) = 2KB.
    __shared__ __align__(16) __bf16 Kf[KCH * 1024];

    const int tid = threadIdx.x;
    const int kc  = blockIdx.x;   // 0..127
    const int qg  = blockIdx.y;   // 0..31
    const int k0  = kc * KCH;

    // ---- stage K chunk: fp32 -> bf16, d padded 24->32, MFMA fragment order ----
    for (int r = tid; r < KCH * SL; r += 256) {
        const int kl = r >> 5;
        const int s  = r & 31;
        const float* src = mem + (size_t)(k0 + kl) * D5 + s * ZD;
        float tv[24];
#pragma unroll
        for (int j = 0; j < 6; ++j) ((float4*)tv)[j] = ((const float4*)src)[j];
        bf16x8 a, b, c, z;
#pragma unroll
        for (int j = 0; j < 8; ++j) {
            a[j] = (__bf16)tv[j];
            b[j] = (__bf16)tv[8 + j];
            c[j] = (__bf16)tv[16 + j];
            z[j] = (__bf16)0.0f;
        }
        __bf16* base = Kf + kl * 1024;
        *(bf16x8*)(base +        s * 8)       = a;  // chunk0, lane s      (d 0-7)
        *(bf16x8*)(base + (32 +  s) * 8)      = b;  // chunk0, lane s+32   (d 8-15)
        *(bf16x8*)(base + 512 +  s * 8)       = c;  // chunk1, lane s      (d 16-23)
        *(bf16x8*)(base + 512 + (32 + s) * 8) = z;  // chunk1, lane s+32   (d 24-31 pad)
    }

    // ---- per-wave Q fragments (held in registers across the whole k-loop) ----
    const int lane = tid & 63;
    const int wv   = tid >> 6;   // 0..3
    const int t    = lane & 31;
    const int h    = lane >> 5;
    const int q    = qg * 4 + wv;

    const float4* p = (const float4*)(tgt + (size_t)q * D5 + t * ZD);
    bf16x8 aQ0, aQ1;
    {
        float4 u0 = p[2 * h], u1 = p[2 * h + 1];  // d = h*8 .. h*8+7
        aQ0[0] = (__bf16)u0.x; aQ0[1] = (__bf16)u0.y; aQ0[2] = (__bf16)u0.z; aQ0[3] = (__bf16)u0.w;
        aQ0[4] = (__bf16)u1.x; aQ0[5] = (__bf16)u1.y; aQ0[6] = (__bf16)u1.z; aQ0[7] = (__bf16)u1.w;
        if (h == 0) {
            float4 w0 = p[4], w1 = p[5];          // d = 16..23
            aQ1[0] = (__bf16)w0.x; aQ1[1] = (__bf16)w0.y; aQ1[2] = (__bf16)w0.z; aQ1[3] = (__bf16)w0.w;
            aQ1[4] = (__bf16)w1.x; aQ1[5] = (__bf16)w1.y; aQ1[6] = (__bf16)w1.z; aQ1[7] = (__bf16)w1.w;
        } else {
#pragma unroll
            for (int j = 0; j < 8; ++j) aQ1[j] = (__bf16)0.0f; // d 24-31 pad
        }
    }
    __syncthreads();

    // ---- pair loop: this wave handles (q, k0+kl) for kl = 0..KCH-1 ----
    for (int kl = 0; kl < KCH; ++kl) {
        const __bf16* lb = Kf + kl * 1024 + lane * 8;
        bf16x8 bK0 = *(const bf16x8*)lb;
        bf16x8 bK1 = *(const bf16x8*)(lb + 512);

        f32x16 accS, accT;
#pragma unroll
        for (int i = 0; i < 16; ++i) { accS[i] = 0.0f; accT[i] = 0.0f; }

        // S[t][s]: A=Q (m=t), B=K (n=s)
        accS = __builtin_amdgcn_mfma_f32_32x32x16_bf16(aQ0, bK0, accS, 0, 0, 0);
        accS = __builtin_amdgcn_mfma_f32_32x32x16_bf16(aQ1, bK1, accS, 0, 0, 0);
        // S^T[s][t]: A=K (m=s), B=Q (n=t)
        accT = __builtin_amdgcn_mfma_f32_32x32x16_bf16(bK0, aQ0, accT, 0, 0, 0);
        accT = __builtin_amdgcn_mfma_f32_32x32x16_bf16(bK1, aQ1, accT, 0, 0, 0);

        // accS: col = s = lane&31, 16 regs span rows t (with lane>>5 half) ->
        //   reg-max = partial max over t  => score.max(axis=3) at fixed s
        // accT: col = t = lane&31, regs span s -> max over s => score.max(axis=2) at fixed t
        float m1 = accS[0], m2 = accT[0];
#pragma unroll
        for (int i = 1; i < 16; ++i) { m1 = fmaxf(m1, accS[i]); m2 = fmaxf(m2, accT[i]); }
        m1 = fmaxf(m1, __shfl_xor(m1, 32));
        m2 = fmaxf(m2, __shfl_xor(m2, 32));

        float v = m1 + m2;                 // per-lane: colmax[l&31] + rowmax[l&31]
        v += __shfl_xor(v, 1);
        v += __shfl_xor(v, 2);
        v += __shfl_xor(v, 4);
        v += __shfl_xor(v, 8);
        v += __shfl_xor(v, 16);            // sum of all 64 maxes, in every lane

        float r = 1.0f / (1.0f + __expf(-v * (1.0f / 64.0f)));
        if (lane == 0) {
            const int idx = q * KN + k0 + kl;
            out[idx] = r;                  // output 0
            out[idx + QN * KN] = r;        // output 1 (tuple returns score_p twice)
        }
    }
}

extern "C" void kernel_launch(void* const* d_in, const int* in_sizes, int n_in,
                              void* d_out, int out_size, void* d_ws, size_t ws_size,
                              hipStream_t stream)
{
    const float* tgt = (const float*)d_in[0];
    const float* mem = (const float*)d_in[1];
    float* out = (float*)d_out;
    dim3 grid(KN / KCH, QN / 4);
    matcher_kernel<<<grid, 256, 0, stream>>>(tgt, mem, out);
}

// Round 2
// 103.911 us; speedup vs baseline: 1.0829x; 1.0829x over previous
//
#include <hip/hip_runtime.h>
#include <hip/hip_bf16.h>

typedef __bf16 bf16x8 __attribute__((ext_vector_type(8)));
typedef float  f32x16 __attribute__((ext_vector_type(16)));

constexpr int QN  = 128;   // query rows
constexpr int KN  = 2048;  // memory rows
constexpr int D5  = 768;
constexpr int SL  = 32;    // seq_len (t and s extent)
constexpr int ZD  = 24;    // per-token sub-dim
constexpr int KCH = 16;    // k's per block

static __device__ __forceinline__ float max3f(float a, float b, float c) {
    return fmaxf(fmaxf(a, b), c);   // fuses to v_max3_f32
}

// 16-element register max as a max3 tree (8 ops instead of 15)
static __device__ __forceinline__ float redmax16(const f32x16& a) {
    float x0 = max3f(a[0],  a[1],  a[2]);
    float x1 = max3f(a[3],  a[4],  a[5]);
    float x2 = max3f(a[6],  a[7],  a[8]);
    float x3 = max3f(a[9],  a[10], a[11]);
    float x4 = max3f(a[12], a[13], a[14]);
    float y0 = max3f(x0, x1, x2);
    float y1 = max3f(x3, x4, a[15]);
    return fmaxf(y0, y1);
}

// Per-pair: S[t][s] = sum_d Q[t][d]*K[s][d] via mfma_f32_32x32x16_bf16 (d padded to 32).
// S^T via a second MFMA pair (operands swapped) so BOTH max-pools are per-lane
// register reductions in the C layout (col=lane&31, rows in the 16 acc regs).
// launch_bounds(256,4): VGPR budget 128 -> accumulators stay in arch VGPRs
// (no v_accvgpr_read/write churn); occupancy is LDS-capped at 5 blocks/CU anyway.
__global__ __launch_bounds__(256, 4) void matcher_kernel(const float* __restrict__ tgt,
                                                         const float* __restrict__ mem,
                                                         float* __restrict__ out)
{
    // Fragment-ordered K chunk: per k, 2 chunks x 64 lanes x 8 bf16 (16B) = 2KB.
    __shared__ __align__(16) __bf16 Kf[KCH * 1024];

    const int tid = threadIdx.x;
    const int kc  = blockIdx.x;   // 0..127
    const int qg  = blockIdx.y;   // 0..31
    const int k0  = kc * KCH;

    // ---- stage K chunk: fp32 -> bf16, d padded 24->32, MFMA fragment order ----
    for (int r = tid; r < KCH * SL; r += 256) {
        const int kl = r >> 5;
        const int s  = r & 31;
        const float* src = mem + (size_t)(k0 + kl) * D5 + s * ZD;
        float tv[24];
#pragma unroll
        for (int j = 0; j < 6; ++j) ((float4*)tv)[j] = ((const float4*)src)[j];
        bf16x8 a, b, c, z;
#pragma unroll
        for (int j = 0; j < 8; ++j) {
            a[j] = (__bf16)tv[j];
            b[j] = (__bf16)tv[8 + j];
            c[j] = (__bf16)tv[16 + j];
            z[j] = (__bf16)0.0f;
        }
        __bf16* base = Kf + kl * 1024;
        *(bf16x8*)(base +        s * 8)       = a;  // chunk0, lane s      (d 0-7)
        *(bf16x8*)(base + (32 +  s) * 8)      = b;  // chunk0, lane s+32   (d 8-15)
        *(bf16x8*)(base + 512 +  s * 8)       = c;  // chunk1, lane s      (d 16-23)
        *(bf16x8*)(base + 512 + (32 + s) * 8) = z;  // chunk1, lane s+32   (d 24-31 pad)
    }

    // ---- per-wave Q fragments (held in registers across the whole k-loop) ----
    const int lane = tid & 63;
    const int wv   = tid >> 6;   // 0..3
    const int t    = lane & 31;
    const int h    = lane >> 5;
    const int q    = qg * 4 + wv;

    const float4* p = (const float4*)(tgt + (size_t)q * D5 + t * ZD);
    bf16x8 aQ0, aQ1;
    {
        float4 u0 = p[2 * h], u1 = p[2 * h + 1];  // d = h*8 .. h*8+7
        aQ0[0] = (__bf16)u0.x; aQ0[1] = (__bf16)u0.y; aQ0[2] = (__bf16)u0.z; aQ0[3] = (__bf16)u0.w;
        aQ0[4] = (__bf16)u1.x; aQ0[5] = (__bf16)u1.y; aQ0[6] = (__bf16)u1.z; aQ0[7] = (__bf16)u1.w;
        if (h == 0) {
            float4 w0 = p[4], w1 = p[5];          // d = 16..23
            aQ1[0] = (__bf16)w0.x; aQ1[1] = (__bf16)w0.y; aQ1[2] = (__bf16)w0.z; aQ1[3] = (__bf16)w0.w;
            aQ1[4] = (__bf16)w1.x; aQ1[5] = (__bf16)w1.y; aQ1[6] = (__bf16)w1.z; aQ1[7] = (__bf16)w1.w;
        } else {
#pragma unroll
            for (int j = 0; j < 8; ++j) aQ1[j] = (__bf16)0.0f; // d 24-31 pad
        }
    }

    // Loop-invariant zero accumulator: passed as C to the first MFMA of each
    // chain, so no per-pair zero-init of the destination is needed.
    f32x16 zacc;
#pragma unroll
    for (int i = 0; i < 16; ++i) zacc[i] = 0.0f;

    __syncthreads();

    // ---- pair loop: this wave handles (q, k0+kl) for kl = 0..KCH-1 ----
    for (int kl = 0; kl < KCH; ++kl) {
        const __bf16* lb = Kf + kl * 1024 + lane * 8;
        bf16x8 bK0 = *(const bf16x8*)lb;
        bf16x8 bK1 = *(const bf16x8*)(lb + 512);

        // S[t][s]: A=Q (m=t), B=K (n=s)
        f32x16 accS = __builtin_amdgcn_mfma_f32_32x32x16_bf16(aQ0, bK0, zacc, 0, 0, 0);
        accS        = __builtin_amdgcn_mfma_f32_32x32x16_bf16(aQ1, bK1, accS, 0, 0, 0);
        // S^T[s][t]: A=K (m=s), B=Q (n=t)
        f32x16 accT = __builtin_amdgcn_mfma_f32_32x32x16_bf16(bK0, aQ0, zacc, 0, 0, 0);
        accT        = __builtin_amdgcn_mfma_f32_32x32x16_bf16(bK1, aQ1, accT, 0, 0, 0);

        // accS: col = s = lane&31, regs+half span rows t -> max = score.max(axis=3)
        // accT: col = t = lane&31, regs+half span s      -> max = score.max(axis=2)
        float m1 = redmax16(accS);
        float m2 = redmax16(accT);
        m1 = fmaxf(m1, __shfl_xor(m1, 32));
        m2 = fmaxf(m2, __shfl_xor(m2, 32));

        float v = m1 + m2;                 // per-lane: colmax[l&31] + rowmax[l&31]
        v += __shfl_xor(v, 1);
        v += __shfl_xor(v, 2);
        v += __shfl_xor(v, 4);
        v += __shfl_xor(v, 8);
        v += __shfl_xor(v, 16);            // sum of all 64 maxes (both halves hold it)

        float r = 1.0f / (1.0f + __expf(-v * (1.0f / 64.0f)));
        if (lane == 0) {
            const int idx = q * KN + k0 + kl;
            out[idx] = r;                  // output 0
            out[idx + QN * KN] = r;        // output 1 (tuple returns score_p twice)
        }
    }
}

extern "C" void kernel_launch(void* const* d_in, const int* in_sizes, int n_in,
                              void* d_out, int out_size, void* d_ws, size_t ws_size,
                              hipStream_t stream)
{
    const float* tgt = (const float*)d_in[0];
    const float* mem = (const float*)d_in[1];
    float* out = (float*)d_out;
    dim3 grid(KN / KCH, QN / 4);
    matcher_kernel<<<grid, 256, 0, stream>>>(tgt, mem, out);
}

// Round 3
// 97.121 us; speedup vs baseline: 1.1586x; 1.0699x over previous
//
#include <hip/hip_runtime.h>
#include <hip/hip_bf16.h>

typedef __bf16 bf16x8 __attribute__((ext_vector_type(8)));
typedef float  f32x16 __attribute__((ext_vector_type(16)));

constexpr int QN  = 128;   // query rows
constexpr int KN  = 2048;  // memory rows
constexpr int D5  = 768;
constexpr int SL  = 32;    // seq_len (t and s extent)
constexpr int ZD  = 24;    // per-token sub-dim
constexpr int KCH = 16;    // k's per block

static __device__ __forceinline__ float max3f(float a, float b, float c) {
    return fmaxf(fmaxf(a, b), c);   // fuses to v_max3_f32
}

// 16-element register max as a max3 tree
static __device__ __forceinline__ float redmax16(const f32x16& a) {
    float x0 = max3f(a[0],  a[1],  a[2]);
    float x1 = max3f(a[3],  a[4],  a[5]);
    float x2 = max3f(a[6],  a[7],  a[8]);
    float x3 = max3f(a[9],  a[10], a[11]);
    float x4 = max3f(a[12], a[13], a[14]);
    float y0 = max3f(x0, x1, x2);
    float y1 = max3f(x3, x4, a[15]);
    return fmaxf(y0, y1);
}

// Per-pair: S[t][s] via mfma_f32_32x32x16_bf16 (d=24 padded to 32) and S^T via a
// second MFMA pair (operands swapped), so BOTH max-pools are per-lane register
// reductions in the C layout (col=lane&31, rows span the 16 acc regs + halves).
//
// R3: epilogue de-serialized. Per pair only 2 independent shfl_xor(32) remain;
// the 32 per-lane maxes are written to a per-wave LDS buffer with XOR-swizzled
// addressing (conflict-free), and ONE batched final phase per wave does the
// 32-value sums + sigmoid + stores for all 16 pairs with full ILP.
__global__ __launch_bounds__(256, 4) void matcher_kernel(const float* __restrict__ tgt,
                                                         const float* __restrict__ mem,
                                                         float* __restrict__ out)
{
    // K fragments: per k, chunk0 = 64 lanes x 16B (d0-15), chunk1 = 32 lanes x 16B
    // (d16-23; upper-half zeros NOT stored - masked read instead). 1536B per k.
    __shared__ __align__(16) __bf16 Kf[KCH * 768];     // 24 KB
    // Per-wave epilogue buffer: [pair][32 swizzled maxes]. 2 KB per wave.
    __shared__ float vbuf[4][KCH * 32];                // 8 KB  (total 32 KB)

    const int tid = threadIdx.x;
    const int kc  = blockIdx.x;   // 0..127
    const int qg  = blockIdx.y;   // 0..31
    const int k0  = kc * KCH;

    // ---- stage K chunk: fp32 -> bf16, MFMA fragment order ----
    for (int r = tid; r < KCH * SL; r += 256) {
        const int kl = r >> 5;
        const int s  = r & 31;
        const float* src = mem + (size_t)(k0 + kl) * D5 + s * ZD;
        float tv[24];
#pragma unroll
        for (int j = 0; j < 6; ++j) ((float4*)tv)[j] = ((const float4*)src)[j];
        bf16x8 a, b, c;
#pragma unroll
        for (int j = 0; j < 8; ++j) {
            a[j] = (__bf16)tv[j];
            b[j] = (__bf16)tv[8 + j];
            c[j] = (__bf16)tv[16 + j];
        }
        __bf16* base = Kf + kl * 768;
        *(bf16x8*)(base +        s * 8)  = a;  // chunk0, lane s      (d 0-7)
        *(bf16x8*)(base + (32 +  s) * 8) = b;  // chunk0, lane s+32   (d 8-15)
        *(bf16x8*)(base + 512 +  s * 8)  = c;  // chunk1, lane s      (d 16-23)
    }

    // ---- per-wave Q fragments (registers, live across the whole k-loop) ----
    const int lane = tid & 63;
    const int wv   = tid >> 6;   // 0..3
    const int t    = lane & 31;
    const int h    = lane >> 5;
    const int q    = qg * 4 + wv;

    const float4* p4 = (const float4*)(tgt + (size_t)q * D5 + t * ZD);
    bf16x8 aQ0, aQ1;
    {
        float4 u0 = p4[2 * h], u1 = p4[2 * h + 1];  // d = h*8 .. h*8+7
        aQ0[0] = (__bf16)u0.x; aQ0[1] = (__bf16)u0.y; aQ0[2] = (__bf16)u0.z; aQ0[3] = (__bf16)u0.w;
        aQ0[4] = (__bf16)u1.x; aQ0[5] = (__bf16)u1.y; aQ0[6] = (__bf16)u1.z; aQ0[7] = (__bf16)u1.w;
        if (h == 0) {
            float4 w0 = p4[4], w1 = p4[5];          // d = 16..23
            aQ1[0] = (__bf16)w0.x; aQ1[1] = (__bf16)w0.y; aQ1[2] = (__bf16)w0.z; aQ1[3] = (__bf16)w0.w;
            aQ1[4] = (__bf16)w1.x; aQ1[5] = (__bf16)w1.y; aQ1[6] = (__bf16)w1.z; aQ1[7] = (__bf16)w1.w;
        } else {
#pragma unroll
            for (int j = 0; j < 8; ++j) aQ1[j] = (__bf16)0.0f; // d 24-31 pad
        }
    }

    // Loop-invariant zero C operand (no per-pair accumulator init).
    f32x16 zacc;
#pragma unroll
    for (int i = 0; i < 16; ++i) zacc[i] = 0.0f;

    __syncthreads();

    float* vb = vbuf[wv];

    // ---- pair loop: this wave handles (q, k0+kl) for kl = 0..KCH-1 ----
#pragma unroll
    for (int kl = 0; kl < KCH; ++kl) {
        const __bf16* lb = Kf + kl * 768;
        bf16x8 bK0 = *(const bf16x8*)(lb + lane * 8);
        bf16x8 bK1;
#pragma unroll
        for (int j = 0; j < 8; ++j) bK1[j] = (__bf16)0.0f;
        if (h == 0) bK1 = *(const bf16x8*)(lb + 512 + t * 8);  // k=0-7 half only

        // S[t][s]: A=Q (m=t), B=K (n=s)
        f32x16 accS = __builtin_amdgcn_mfma_f32_32x32x16_bf16(aQ0, bK0, zacc, 0, 0, 0);
        accS        = __builtin_amdgcn_mfma_f32_32x32x16_bf16(aQ1, bK1, accS, 0, 0, 0);
        // S^T[s][t]: A=K (m=s), B=Q (n=t)
        f32x16 accT = __builtin_amdgcn_mfma_f32_32x32x16_bf16(bK0, aQ0, zacc, 0, 0, 0);
        accT        = __builtin_amdgcn_mfma_f32_32x32x16_bf16(bK1, aQ1, accT, 0, 0, 0);

        // accS: col=s=lane&31, regs+halves span t -> max over t = score.max(axis=3)
        // accT: col=t=lane&31, regs+halves span s -> max over s = score.max(axis=2)
        float m1 = redmax16(accS);
        float m2 = redmax16(accT);
        m1 = fmaxf(m1, __shfl_xor(m1, 32));   // two INDEPENDENT half-combines
        m2 = fmaxf(m2, __shfl_xor(m2, 32));
        float v = m1 + m2;                    // per-lane: axis3max[s] + axis2max[t]
        // XOR-swizzled store: pair kl, slot t -> word kl*32 + (t^kl). Conflict-free.
        if (h == 0) vb[(kl << 5) + (t ^ kl)] = v;
    }

    // ---- batched final phase (per wave, no barrier: same-wave LDS reuse) ----
    // Pair p's 32 values summed by lane pair (p, p+16); lanes 32-63 duplicate.
    {
        const int p    = lane & 15;
        const int half = (lane >> 4) & 1;
        float x[16];
#pragma unroll
        for (int i = 0; i < 16; ++i)
            x[i] = vb[(p << 5) + ((half << 4) + i ^ p)];  // conflict-free scalar reads
        // pairwise add tree (full ILP)
        float s0 = (x[0] + x[1]) + (x[2] + x[3]);
        float s1 = (x[4] + x[5]) + (x[6] + x[7]);
        float s2 = (x[8] + x[9]) + (x[10] + x[11]);
        float s3 = (x[12] + x[13]) + (x[14] + x[15]);
        float sum = (s0 + s1) + (s2 + s3);
        sum += __shfl_xor(sum, 16);           // combine halves of the 32-sum
        float r = 1.0f / (1.0f + __expf(-sum * (1.0f / 64.0f)));
        if (lane < 16) {
            const int idx = q * KN + k0 + p;
            out[idx] = r;                     // output 0
            out[idx + QN * KN] = r;           // output 1 (tuple repeats score_p)
        }
    }
}

extern "C" void kernel_launch(void* const* d_in, const int* in_sizes, int n_in,
                              void* d_out, int out_size, void* d_ws, size_t ws_size,
                              hipStream_t stream)
{
    const float* tgt = (const float*)d_in[0];
    const float* mem = (const float*)d_in[1];
    float* out = (float*)d_out;
    dim3 grid(KN / KCH, QN / 4);
    matcher_kernel<<<grid, 256, 0, stream>>>(tgt, mem, out);
}